// Round 13
// baseline (245.230 us; speedup 1.0000x reference)
//
#include <hip/hip_runtime.h>

// MultiHeadattention: B=2, S=2048, D=1024, H=16, Dk=64.
// QUIRK: softmax over the HEAD axis (dim=1): attn[b,h,q,k] = exp(s)/sum_h' exp(s').
// R9: log-space softmax (Q pre-scaled by 0.125*log2e; zker2 stores lrz=-log2(Z);
// attn4 C-inits QK MFMA with lrz -> p = exp2(sf)); XCD-aware block swizzle.
// R12: attn4 = exact R9 body (VGPR 64 / 16KB LDS -> 8 blocks/CU, TLP does hiding).
// R14: cvt merges. R15: attn4 KS=4 XCD swizzle (FETCH 105->40MB, -3.6us).
// R16 NULL: zker TLP. R17 NULL: GEMM L2-partition. R18: osum3 dbuf (-2us).
// R19: qkv4 128x64 tile, 6 blocks/CU (-13.8us) -> 238.9us BEST (reproduced R21).
// R20 REGRESSED: psum fold into osum (VGPR bloat at 2 blocks/CU).
// R22: attn4 addressing strength-reduction. VALU-issue is ~31us vs ~7us
// irreducible exp2 -> bloat. The kt loop recomputed 64-bit address chains
// ((hb+kbase+row)*DKH etc.) every iteration. Now: 32-bit element offsets
// computed ONCE, incremented by constants (K += 64*DKH, V/rz += 64); rz
// (qs,gr) offsets derived from one base (+qs*32768 + gr*32). 5 persistent
// 32-bit regs added, recompute temporaries removed -> VGPR must stay 64.

#define D_MODEL 1024
#define NH 16
#define DKH 64
#define SEQ 2048
#define NB 2
#define NTOK (NB * SEQ)
#define OSC 0.180336880f   // 0.125 * log2(e)

typedef float f32x4 __attribute__((ext_vector_type(4)));
typedef short bf16x8 __attribute__((ext_vector_type(8)));

static __device__ __forceinline__ unsigned short f2bf(float x) {
    union { float f; unsigned int u; } c; c.f = x;
    unsigned int r = (c.u + 0x7FFFu + ((c.u >> 16) & 1u)) >> 16;
    return (unsigned short)r;
}
static __device__ __forceinline__ unsigned int pack2(float a, float b) {
    return (unsigned int)f2bf(a) | ((unsigned int)f2bf(b) << 16);
}
static __device__ __forceinline__ unsigned int pack2rn(float a, float b) {
    union { float f; unsigned int u; } ca, cb; ca.f = a; cb.f = b;
    return __builtin_amdgcn_perm(cb.u + 0x8000u, ca.u + 0x8000u, 0x07060302u);
}
// truncating pack (1 inst) — inner-loop P only (P>0, bias ~2^-9)
static __device__ __forceinline__ unsigned int pack2tr(float a, float b) {
    union { float f; unsigned int u; } ca, cb; ca.f = a; cb.f = b;
    return __builtin_amdgcn_perm(cb.u, ca.u, 0x07060302u);
}
static __device__ __forceinline__ float bflo(unsigned int u) {
    union { unsigned int x; float f; } c; c.x = u << 16; return c.f;
}
static __device__ __forceinline__ float bfhi(unsigned int u) {
    union { unsigned int x; float f; } c; c.x = u & 0xFFFF0000u; return c.f;
}
static __device__ __forceinline__ f32x4 mfma16(uint4 a, uint4 b, f32x4 c) {
    return __builtin_amdgcn_mfma_f32_16x16x32_bf16(
        __builtin_bit_cast(bf16x8, a), __builtin_bit_cast(bf16x8, b), c, 0, 0, 0);
}
static __device__ __forceinline__ void gl_lds16(const unsigned short* g, unsigned short* l) {
    __builtin_amdgcn_global_load_lds(
        (const __attribute__((address_space(1))) unsigned int*)g,
        (__attribute__((address_space(3))) unsigned int*)l, 16, 0, 0);
}
static __device__ __forceinline__ int fsw(int row) {
    return (row & 7) ^ ((row >> 2) & 7);
}

// ---------------- fp32 -> bf16: x + three W's in ONE dispatch ----------------
// blocks [0,2048): x -> xb.  blocks [2048,3584): Wq/Wk/Wv -> Wb3.
__global__ __launch_bounds__(256) void cvt4(
    const float* __restrict__ x, const float* __restrict__ w0,
    const float* __restrict__ w1, const float* __restrict__ w2,
    unsigned short* __restrict__ xb, unsigned short* __restrict__ Wb3)
{
    int bid = blockIdx.x;
    const float* src;
    unsigned short* dst;
    size_t i;
    if (bid < 2048) {
        src = x; dst = xb;
        i = ((size_t)bid * 256 + threadIdx.x) * 8;
    } else {
        int r = bid - 2048;
        int sel = r >> 9, blk = r & 511;
        src = (sel == 0) ? w0 : (sel == 1) ? w1 : w2;
        dst = Wb3 + (size_t)sel * D_MODEL * D_MODEL;
        i = ((size_t)blk * 256 + threadIdx.x) * 8;
    }
    float4 a = *(const float4*)(src + i);
    float4 b = *(const float4*)(src + i + 4);
    uint4 p = { pack2(a.x, a.y), pack2(a.z, a.w), pack2(b.x, b.y), pack2(b.z, b.w) };
    *(uint4*)(dst + i) = p;
}

// ---------------- fp32 -> bf16 copy (KS==1 fallback for Wo) ----------------
__global__ __launch_bounds__(256) void cvt_k(const float* __restrict__ x,
                                             unsigned short* __restrict__ xb)
{
    size_t i = ((size_t)blockIdx.x * 256 + threadIdx.x) * 8;
    float4 a = *(const float4*)(x + i);
    float4 b = *(const float4*)(x + i + 4);
    uint4 p = { pack2(a.x, a.y), pack2(a.z, a.w), pack2(b.x, b.y), pack2(b.z, b.w) };
    *(uint4*)(xb + i) = p;
}

// ---------------- fused QKV GEMM, 128x64 tile, XCD-partitioned ----------------
// sel: 0 Q (osc=OSC, per-head), 1 K (per-head), 2 V (Vt transpose).
// R19: 1536 blocks = 6 blocks/CU = 24 waves/CU. Waves 2m x 2n; per wave
// 64m x 32n (acc[4][2]). xcd = (mg 0..3)*2 + (sg 0..1); slot m-inner.
__global__ __launch_bounds__(256) void gemm_qkv4(
    const unsigned short* __restrict__ A, const unsigned short* __restrict__ Wb3,
    const float* __restrict__ bq, const float* __restrict__ bk,
    const float* __restrict__ bv, unsigned short* __restrict__ Qh,
    unsigned short* __restrict__ Kh, unsigned short* __restrict__ Vt)
{
    __shared__ unsigned short lds[12288];   // 24 KB: lA 128x64 | lB 64x64
    unsigned short* lA = lds;          // 8192 u16
    unsigned short* lB = lds + 8192;   // 4096 u16
    const int tid = threadIdx.x;
    const int wv = tid >> 6, lane = tid & 63, quad = lane >> 4, lm = lane & 15;
    const int wm = wv >> 1, wn = wv & 1;
    const int bid = blockIdx.x;
    const int xcd = bid & 7, slot = bid >> 3;      // slot 0..191
    const int mg = xcd >> 1, sg = xcd & 1;
    const int mtile = mg * 8 + (slot & 7);         // 0..31
    const int sn = sg * 24 + (slot >> 3);          // 0..47
    const int sel = sn >> 4;                       // 0..2
    const int ncol = sn & 15;                      // 0..15
    const int m0 = mtile * 128, n0 = ncol * 64;
    const int sub = lane >> 3, chl = (lane & 7) ^ sub;
    const unsigned short* Wb = Wb3 + (size_t)sel * D_MODEL * D_MODEL;
    const float* bias = (sel == 0) ? bq : (sel == 1) ? bk : bv;
    const float osc = (sel == 0) ? OSC : 1.0f;

    f32x4 acc[4][2] = {};

    for (int k0 = 0; k0 < D_MODEL; k0 += 64) {
        __syncthreads();
#pragma unroll
        for (int j = 0; j < 4; ++j) {
            int rbase = wv * 32 + j * 8;
            gl_lds16(A + (size_t)(m0 + rbase + sub) * D_MODEL + k0 + chl * 8,
                     &lA[rbase * 64]);
        }
#pragma unroll
        for (int j = 0; j < 2; ++j) {
            int rbase = wv * 16 + j * 8;
            gl_lds16(Wb + (size_t)(n0 + rbase + sub) * D_MODEL + k0 + chl * 8,
                     &lB[rbase * 64]);
        }
        __syncthreads();
#pragma unroll
        for (int ks = 0; ks < 2; ++ks) {
            uint4 af[4];
#pragma unroll
            for (int mt = 0; mt < 4; ++mt)
                af[mt] = *(const uint4*)&lA[(wm * 64 + mt * 16 + lm) * 64 +
                                            ((ks * 4 + quad) ^ (lm & 7)) * 8];
#pragma unroll
            for (int nt = 0; nt < 2; ++nt) {
                uint4 bf = *(const uint4*)&lB[(wn * 32 + nt * 16 + lm) * 64 +
                                              ((ks * 4 + quad) ^ (lm & 7)) * 8];
#pragma unroll
                for (int mt = 0; mt < 4; ++mt)
                    acc[mt][nt] = mfma16(af[mt], bf, acc[mt][nt]);
            }
        }
    }

    if (sel < 2) {
        unsigned short* out = (sel == 0) ? Qh : Kh;
#pragma unroll
        for (int nt = 0; nt < 2; ++nt) {
            int n = n0 + wn * 32 + nt * 16 + lm;
            float bvv = bias[n];
            int h = n >> 6, d = n & 63;
#pragma unroll
            for (int mt = 0; mt < 4; ++mt)
#pragma unroll
                for (int r = 0; r < 4; ++r) {
                    int m = m0 + wm * 64 + mt * 16 + quad * 4 + r;
                    int b = m >> 11, q = m & 2047;
                    out[((size_t)(b * NH + h) * SEQ + q) * DKH + d] =
                        f2bf((acc[mt][nt][r] + bvv) * osc);
                }
        }
    } else {
        __syncthreads();
        unsigned short* T = lds;   // 64 n x 128 m u16 (16 KB)
#pragma unroll
        for (int nt = 0; nt < 2; ++nt) {
            int nl = wn * 32 + nt * 16 + lm;
            float bvv = bias[n0 + nl];
#pragma unroll
            for (int mt = 0; mt < 4; ++mt) {
                int ml = wm * 64 + mt * 16 + quad * 4;
                uint2 p = { pack2rn(acc[mt][nt][0] + bvv, acc[mt][nt][1] + bvv),
                            pack2rn(acc[mt][nt][2] + bvv, acc[mt][nt][3] + bvv) };
                *(uint2*)&T[nl * 128 + ml] = p;
            }
        }
        __syncthreads();
        int row = tid >> 2, seg = tid & 3;     // 64 rows x 4 segs of 32 u16
        int b = m0 >> 11, s0 = m0 & 2047;
        unsigned short* dst = Vt + ((size_t)(b * D_MODEL) + n0 + row) * SEQ + s0 + seg * 32;
        const unsigned short* src = &T[row * 128 + seg * 32];
#pragma unroll
        for (int i = 0; i < 4; ++i)
            *(uint4*)(dst + i * 8) = *(const uint4*)(src + i * 8);
    }
}

// ---------------- psum_wo: fold KS partials + convert Wo, ONE dispatch ----------
// blocks [0,2048): psum. blocks [2048,2560): Wo fp32->bf16.
template <int KS>
__global__ __launch_bounds__(256) void psum_wo(
    const unsigned short* __restrict__ OP, unsigned short* __restrict__ OPs,
    const float* __restrict__ Wo, unsigned short* __restrict__ WoB)
{
    int bid = blockIdx.x;
    if (bid >= 2048) {
        size_t i = ((size_t)(bid - 2048) * 256 + threadIdx.x) * 8;
        float4 a = *(const float4*)(Wo + i);
        float4 b = *(const float4*)(Wo + i + 4);
        uint4 p = { pack2(a.x, a.y), pack2(a.z, a.w), pack2(b.x, b.y), pack2(b.z, b.w) };
        *(uint4*)(WoB + i) = p;
        return;
    }
    const size_t M = (size_t)NTOK * D_MODEL;
    size_t i = ((size_t)bid * 256 + threadIdx.x) * 8;
    uint4 a = *(const uint4*)(OP + i);
    float lo0 = bflo(a.x), hi0 = bfhi(a.x), lo1 = bflo(a.y), hi1 = bfhi(a.y);
    float lo2 = bflo(a.z), hi2 = bfhi(a.z), lo3 = bflo(a.w), hi3 = bfhi(a.w);
#pragma unroll
    for (int p = 1; p < KS; ++p) {
        uint4 u = *(const uint4*)(OP + p * M + i);
        lo0 += bflo(u.x); hi0 += bfhi(u.x); lo1 += bflo(u.y); hi1 += bfhi(u.y);
        lo2 += bflo(u.z); hi2 += bfhi(u.z); lo3 += bflo(u.w); hi3 += bfhi(u.w);
    }
    uint4 o = { pack2(lo0, hi0), pack2(lo1, hi1), pack2(lo2, hi2), pack2(lo3, hi3) };
    *(uint4*)(OPs + i) = o;
}

// ---------------- out-proj: A = folded ctx (bf16), B = Wo bf16; fp32 out --------
// R11 tile: 128x64, waves 2m x 2n (acc[4][2]); R17 XCD m-inner partition.
// R18: double-buffered LDS (48 KB, still 2 blocks/CU at grid 512 — free):
// stage(next) -> compute(cur) -> ONE barrier.
__global__ __launch_bounds__(256) void gemm_osum3(
    const unsigned short* __restrict__ OPs, const unsigned short* __restrict__ WoB,
    const float* __restrict__ bias, float* __restrict__ out)
{
    __shared__ unsigned short lds[2][12288];   // 48 KB: per buf lA 128x64 | lB 64x64
    const int tid = threadIdx.x;
    const int wv = tid >> 6, lane = tid & 63, quad = lane >> 4, lm = lane & 15;
    const int wm = wv >> 1, wn = wv & 1;
    const int bid = blockIdx.x;
    const int xcd = bid & 7, slot = bid >> 3;          // slot 0..63
    const int mg = xcd >> 1, ng = xcd & 1;
    const int mtile = mg * 8 + (slot & 7);             // 0..31
    const int ncol = ng * 8 + (slot >> 3);             // 0..15
    const int m0 = mtile * 128, n0 = ncol * 64;
    const int sub = lane >> 3, chl = (lane & 7) ^ sub;
    const int b = m0 >> 11, q0 = m0 & 2047;

    f32x4 acc[4][2] = {};

    auto stage = [&](int buf, int k0) {
        const int h = k0 >> 6;
        const unsigned short* Ab = OPs + ((size_t)(b * NH + h) * SEQ + q0) * DKH;
        unsigned short* lA = lds[buf];
        unsigned short* lB = lds[buf] + 8192;
#pragma unroll
        for (int j = 0; j < 4; ++j) {
            int rbase = wv * 32 + j * 8;
            gl_lds16(Ab + (size_t)(rbase + sub) * DKH + chl * 8, &lA[rbase * 64]);
        }
#pragma unroll
        for (int j = 0; j < 2; ++j) {
            int rbase = wv * 16 + j * 8;
            gl_lds16(WoB + (size_t)(n0 + rbase + sub) * D_MODEL + k0 + chl * 8,
                     &lB[rbase * 64]);
        }
    };

    stage(0, 0);
    __syncthreads();

    for (int k0 = 0; k0 < D_MODEL; k0 += 64) {
        const int cur = (k0 >> 6) & 1;
        if (k0 + 64 < D_MODEL)
            stage(cur ^ 1, k0 + 64);   // overlaps this step's compute
        const unsigned short* lA = lds[cur];
        const unsigned short* lB = lds[cur] + 8192;
#pragma unroll
        for (int ks = 0; ks < 2; ++ks) {
            uint4 af[4];
#pragma unroll
            for (int mt = 0; mt < 4; ++mt)
                af[mt] = *(const uint4*)&lA[(wm * 64 + mt * 16 + lm) * 64 +
                                            ((ks * 4 + quad) ^ (lm & 7)) * 8];
#pragma unroll
            for (int nt = 0; nt < 2; ++nt) {
                uint4 bf = *(const uint4*)&lB[(wn * 32 + nt * 16 + lm) * 64 +
                                              ((ks * 4 + quad) ^ (lm & 7)) * 8];
#pragma unroll
                for (int mt = 0; mt < 4; ++mt)
                    acc[mt][nt] = mfma16(af[mt], bf, acc[mt][nt]);
            }
        }
        __syncthreads();   // next-tile stage landed; buffer reuse safe
    }
#pragma unroll
    for (int nt = 0; nt < 2; ++nt) {
        int n = n0 + wn * 32 + nt * 16 + lm;
        float bv = bias[n];
#pragma unroll
        for (int mt = 0; mt < 4; ++mt)
#pragma unroll
            for (int r = 0; r < 4; ++r) {
                int m = m0 + wm * 64 + mt * 16 + quad * 4 + r;
                out[(size_t)m * D_MODEL + n] = acc[mt][nt][r] + bv;
            }
    }
}

// ---------------- zker2: lrz[b][q][k] = -log2(sum_h exp2(S_scaled)) ----------
// R10/R12 (proven): double-buffered K staging + next-head Q prefetch;
// 1 barrier/head. (R16: 4 blocks/CU variant was null — structure, not TLP, binds.)
__global__ __launch_bounds__(256) void zker2(
    const unsigned short* __restrict__ Qh, const unsigned short* __restrict__ Kh,
    unsigned short* __restrict__ rz)
{
    __shared__ unsigned short lK[2][128 * 64];  // 32 KB
    const int tid = threadIdx.x;
    const int wv = tid >> 6, lane = tid & 63, quad = lane >> 4, lm = lane & 15;
    // swizzle: XCD owns 4 (b,kb) columns x all 16 qb (qb adjacent -> K slab shared)
    const int lid = blockIdx.x;
    const int xcd = lid & 7, slot = lid >> 3;
    const int qb = slot & 15, col = xcd * 4 + (slot >> 4);
    const int b = col >> 4, kb = col & 15;
    const int q0 = qb * 128, k0 = kb * 128;
    const int srow = tid >> 3, sc = tid & 7;

    f32x4 z[2][8] = {};

    auto stagek = [&](int buf, int hh) {
        const size_t kbase = ((size_t)(b * NH + hh) * SEQ + k0) * DKH;
#pragma unroll
        for (int j = 0; j < 4; ++j) {
            int row = j * 32 + srow;
            int g = sc ^ fsw(row);
            gl_lds16(Kh + kbase + (size_t)row * 64 + g * 8,
                     &lK[buf][(j * 32 + wv * 8) * 64]);
        }
    };
    auto loadq = [&](uint4 (&bqr)[2][2], int hh) {
#pragma unroll
        for (int qs = 0; qs < 2; ++qs) {
            const unsigned short* qp = Qh +
                ((size_t)(b * NH + hh) * SEQ + q0 + wv * 32 + qs * 16 + lm) * DKH + quad * 8;
            bqr[qs][0] = *(const uint4*)qp;
            bqr[qs][1] = *(const uint4*)(qp + 32);
        }
    };

    uint4 bq[2][2];
    stagek(0, 0);
    loadq(bq, 0);
    __syncthreads();

    for (int h = 0; h < NH; ++h) {
        const int cur = h & 1;
        uint4 bqn[2][2];
        if (h + 1 < NH) {
            stagek(cur ^ 1, h + 1);   // overlaps this head's compute
            loadq(bqn, h + 1);
        }
        const unsigned short* cK = lK[cur];
#pragma unroll
        for (int kt = 0; kt < 8; ++kt) {
            int krow = kt * 16 + lm;
            uint4 a0 = *(const uint4*)&cK[krow * 64 + ((quad) ^ fsw(krow)) * 8];
            uint4 a1 = *(const uint4*)&cK[krow * 64 + ((4 + quad) ^ fsw(krow)) * 8];
#pragma unroll
            for (int qs = 0; qs < 2; ++qs) {
                f32x4 sf = {0.f, 0.f, 0.f, 0.f};
                __builtin_amdgcn_s_setprio(1);
                sf = mfma16(a0, bq[qs][0], sf);
                sf = mfma16(a1, bq[qs][1], sf);
                __builtin_amdgcn_s_setprio(0);
#pragma unroll
                for (int r = 0; r < 4; ++r)
                    z[qs][kt][r] += __builtin_amdgcn_exp2f(sf[r]);
            }
        }
        __syncthreads();   // next K slab landed (issued a full compute phase ago)
        if (h + 1 < NH) {
#pragma unroll
            for (int qs = 0; qs < 2; ++qs) {
                bq[qs][0] = bqn[qs][0];
                bq[qs][1] = bqn[qs][1];
            }
        }
    }
#pragma unroll
    for (int qs = 0; qs < 2; ++qs) {
        int q = q0 + wv * 32 + qs * 16 + lm;
#pragma unroll
        for (int kt = 0; kt < 8; ++kt) {
            int k = k0 + kt * 16 + quad * 4;
            float l0 = __builtin_amdgcn_logf(z[qs][kt][0]);
            float l1 = __builtin_amdgcn_logf(z[qs][kt][1]);
            float l2 = __builtin_amdgcn_logf(z[qs][kt][2]);
            float l3 = __builtin_amdgcn_logf(z[qs][kt][3]);
            uint2 st = { pack2rn(-l0, -l1), pack2rn(-l2, -l3) };
            *(uint2*)(rz + (size_t)(b * SEQ + q) * SEQ + k) = st;
        }
    }
}

// ---------------- attn4: per-head attention; lrz as MFMA C-init; XCD-swizzled ----------
// R12: exact R9 body (VGPR 64, 16KB LDS, 8 blocks/CU).
// R15 (KS=4): xcd owns one (b,ksl); slot = qb*16 + h (FETCH 105->40MB).
// R22: 32-bit offset strength-reduction — K/V/rz element offsets computed once,
// incremented by constants per kt (no per-iteration 64-bit address chains).
template <int KS>
__global__ __launch_bounds__(256) void attn4(
    const unsigned short* __restrict__ Qh, const unsigned short* __restrict__ Kh,
    const unsigned short* __restrict__ Vt, const unsigned short* __restrict__ rz,
    unsigned short* __restrict__ OP)
{
    __shared__ unsigned short lK[64 * 64];   // 8 KB
    __shared__ unsigned short lV[64 * 64];   // 8 KB
    const int tid = threadIdx.x;
    const int wv = tid >> 6, lane = tid & 63, quad = lane >> 4, lm = lane & 15;
    const int lid = blockIdx.x;
    int b, h, ksl, qb;
    if constexpr (KS == 4) {
        // R15 swizzle: 2048 = 8 xcd x 256 slot; xcd <-> (b,ksl); slot = qb*16+h
        const int xcd = lid & 7, slot = lid >> 3;
        b = xcd >> 2; ksl = xcd & 3;
        qb = slot >> 4; h = slot & 15;
    } else {
        // generic swizzle: XCD owns 4*KS (bh,ksl) combos x all 16 qb
        const int xcd = lid & 7, slot = lid >> 3;
        qb = slot & 15;
        const int combo = xcd * (4 * KS) + (slot >> 4);
        const int bh = combo / KS; ksl = combo % KS;
        b = bh >> 4; h = bh & 15;
    }
    const int q0 = qb * 128;
    const int NIT = (SEQ / KS) / 64;
    const int kbeg = ksl * (SEQ / KS);
    const int q0w = q0 + wv * 32;
    const size_t hb = (size_t)(b * NH + h) * SEQ;
    const int srow = tid >> 3, sc = tid & 7;

    uint4 qf[2][2];
#pragma unroll
    for (int qs = 0; qs < 2; ++qs)
#pragma unroll
        for (int ks = 0; ks < 2; ++ks)
            qf[qs][ks] = *(const uint4*)(Qh + (hb + q0w + qs * 16 + lm) * DKH +
                                         ks * 32 + quad * 8);

    const int perm = ((lm >> 2) * 8) + (lm & 3);
    f32x4 oa[4][2] = {};

    // R22: persistent 32-bit element offsets, constant per-kt increments.
    int koff[2], voff[2];
#pragma unroll
    for (int j = 0; j < 2; ++j) {
        int row = j * 32 + srow;
        int g = sc ^ fsw(row);
        koff[j] = (int)((hb + kbeg + row) * DKH) + g * 8;
        voff[j] = (b * D_MODEL + h * DKH + row) * SEQ + kbeg + g * 8;
    }
    int roff = (int)(((size_t)(b * SEQ + q0w + lm)) * SEQ) + kbeg + quad * 8;

    for (int kt = 0; kt < NIT; ++kt) {
        __syncthreads();
#pragma unroll
        for (int j = 0; j < 2; ++j)
            gl_lds16(Kh + koff[j], &lK[(j * 32 + wv * 8) * 64]);
#pragma unroll
        for (int j = 0; j < 2; ++j)
            gl_lds16(Vt + voff[j], &lV[(j * 32 + wv * 8) * 64]);
        uint4 rv[2][2];
#pragma unroll
        for (int qs = 0; qs < 2; ++qs)
#pragma unroll
            for (int gr = 0; gr < 2; ++gr)
                rv[gr][qs] = *(const uint4*)(rz + roff +
                                             qs * (16 * SEQ) + gr * 32);
        __syncthreads();
#pragma unroll
        for (int j = 0; j < 2; ++j) { koff[j] += 64 * DKH; voff[j] += 64; }
        roff += 64;

#pragma unroll
        for (int gr = 0; gr < 2; ++gr) {
            // C-init with lrz: sf = QK^T_scaled - log2(Z); then p = exp2(sf)
            f32x4 sf[2][2];
#pragma unroll
            for (int qs = 0; qs < 2; ++qs) {
                uint4 rq = rv[gr][qs];
                sf[0][qs][0] = bflo(rq.x); sf[0][qs][1] = bfhi(rq.x);
                sf[0][qs][2] = bflo(rq.y); sf[0][qs][3] = bfhi(rq.y);
                sf[1][qs][0] = bflo(rq.z); sf[1][qs][1] = bfhi(rq.z);
                sf[1][qs][2] = bflo(rq.w); sf[1][qs][3] = bfhi(rq.w);
            }
#pragma unroll
            for (int sel = 0; sel < 2; ++sel) {
                int key = gr * 32 + perm + sel * 4;
#pragma unroll
                for (int ks = 0; ks < 2; ++ks) {
                    uint4 kfv = *(const uint4*)&lK[key * 64 +
                                                   ((ks * 4 + quad) ^ fsw(key)) * 8];
                    sf[sel][0] = mfma16(kfv, qf[0][ks], sf[sel][0]);
                    sf[sel][1] = mfma16(kfv, qf[1][ks], sf[sel][1]);
                }
            }
            uint4 pk[2];
#pragma unroll
            for (int qs = 0; qs < 2; ++qs) {
                float p00 = __builtin_amdgcn_exp2f(sf[0][qs][0]);
                float p01 = __builtin_amdgcn_exp2f(sf[0][qs][1]);
                float p02 = __builtin_amdgcn_exp2f(sf[0][qs][2]);
                float p03 = __builtin_amdgcn_exp2f(sf[0][qs][3]);
                float p10 = __builtin_amdgcn_exp2f(sf[1][qs][0]);
                float p11 = __builtin_amdgcn_exp2f(sf[1][qs][1]);
                float p12 = __builtin_amdgcn_exp2f(sf[1][qs][2]);
                float p13 = __builtin_amdgcn_exp2f(sf[1][qs][3]);
                pk[qs].x = pack2tr(p00, p01);
                pk[qs].y = pack2tr(p02, p03);
                pk[qs].z = pack2tr(p10, p11);
                pk[qs].w = pack2tr(p12, p13);
            }
#pragma unroll
            for (int ct = 0; ct < 4; ++ct) {
                int vrow = ct * 16 + lm;
                uint4 vfv = *(const uint4*)&lV[vrow * 64 +
                                               ((gr * 4 + quad) ^ fsw(vrow)) * 8];
                oa[ct][0] = mfma16(vfv, pk[0], oa[ct][0]);
                oa[ct][1] = mfma16(vfv, pk[1], oa[ct][1]);
            }
        }
    }

    unsigned short* op = OP + (size_t)ksl * NTOK * D_MODEL;
#pragma unroll
    for (int ct = 0; ct < 4; ++ct)
#pragma unroll
        for (int qs = 0; qs < 2; ++qs) {
            uint2 st = { pack2rn(oa[ct][qs][0], oa[ct][qs][1]),
                         pack2rn(oa[ct][qs][2], oa[ct][qs][3]) };
            *(uint2*)(op + (hb + q0w + qs * 16 + lm) * DKH + ct * 16 + quad * 4) = st;
        }
}

extern "C" void kernel_launch(void* const* d_in, const int* in_sizes, int n_in,
                              void* d_out, int out_size, void* d_ws, size_t ws_size,
                              hipStream_t stream)
{
    const float* x  = (const float*)d_in[0];
    const float* Wq = (const float*)d_in[1];
    const float* bq = (const float*)d_in[2];
    const float* Wk = (const float*)d_in[3];
    const float* bk = (const float*)d_in[4];
    const float* Wv = (const float*)d_in[5];
    const float* bv = (const float*)d_in[6];
    const float* Wo = (const float*)d_in[7];
    const float* bo = (const float*)d_in[8];
    float* out = (float*)d_out;

    const size_t M  = (size_t)NTOK * D_MODEL;      // 4,194,304
    const size_t RZ = (size_t)NB * SEQ * SEQ;      // 8,388,608
    unsigned short* ws = (unsigned short*)d_ws;
    unsigned short* rzb = ws;            // lrz; also xb early, WoB late
    unsigned short* xb  = ws;
    unsigned short* Qh  = ws + RZ;       // per-head [(b,h,q)][dk], Q pre-scaled by OSC
    unsigned short* Kh  = Qh + M;
    unsigned short* Vt  = Kh + M;        // [b][c][s]
    unsigned short* OP  = Vt + M;        // KS per-head partials; early alias: Wb3
    unsigned short* Wb3 = OP;
    unsigned short* OPs = Qh;            // folded ctx (Qh dead after attn4)
    unsigned short* WoB = rzb;           // bf16 Wo (lrz dead after attn4)

    const size_t need4 = (RZ + 3 * M + 4 * M) * sizeof(unsigned short);  // 75.5 MB
    const size_t need2 = (RZ + 3 * M + 2 * M) * sizeof(unsigned short);  // 58.7 MB
    const int KS = (ws_size >= need4) ? 4 : (ws_size >= need2) ? 2 : 1;

    cvt4<<<3584, 256, 0, stream>>>(x, Wq, Wk, Wv, xb, Wb3);
    gemm_qkv4<<<1536, 256, 0, stream>>>(xb, Wb3, bq, bk, bv, Qh, Kh, Vt);
    zker2<<<512, 256, 0, stream>>>(Qh, Kh, rzb);
    if (KS == 4)      attn4<4><<<2048, 256, 0, stream>>>(Qh, Kh, Vt, rzb, OP);
    else if (KS == 2) attn4<2><<<1024, 256, 0, stream>>>(Qh, Kh, Vt, rzb, OP);
    else              attn4<1><<<512, 256, 0, stream>>>(Qh, Kh, Vt, rzb, OP);
    if (KS == 4)      psum_wo<4><<<2560, 256, 0, stream>>>(OP, OPs, Wo, WoB);
    else if (KS == 2) psum_wo<2><<<2560, 256, 0, stream>>>(OP, OPs, Wo, WoB);
    else {
        cvt_k<<<512, 256, 0, stream>>>(Wo, WoB);
        OPs = OP;
    }
    gemm_osum3<<<dim3(512), 256, 0, stream>>>(OPs, WoB, bo, out);
}

// Round 14
// 237.915 us; speedup vs baseline: 1.0307x; 1.0307x over previous
//
#include <hip/hip_runtime.h>

// MultiHeadattention: B=2, S=2048, D=1024, H=16, Dk=64.
// QUIRK: softmax over the HEAD axis (dim=1): attn[b,h,q,k] = exp(s)/sum_h' exp(s').
// R9: log-space softmax (Q pre-scaled by 0.125*log2e; zker2 stores lrz=-log2(Z);
// attn4 C-inits QK MFMA with lrz -> p = exp2(sf)); XCD-aware block swizzle.
// R12: attn4 = exact R9 body (VGPR 64 / 16KB LDS -> 8 blocks/CU, TLP does hiding).
// R14: cvt merges. R15: attn4 KS=4 XCD swizzle (FETCH 105->40MB, -3.6us).
// R16 NULL: zker TLP. R17 NULL: GEMM L2-partition. R18: osum3 dbuf (-2us).
// R19: qkv4 128x64 tile, 6 blocks/CU (-13.8us) -> 238.9us BEST (reproduced R21
// at 239.3). R20 REGRESSED: psum fold into osum. R22 NEUTRAL: attn4 addr
// strength-reduction (VGPR 64->60, dur flat -> compiler already hoisted; the
// VALU stream is the unpack/exp2/pack core, irreducible at HIP level).
// R23: final revert to the twice-proven R19/R21 configuration.

#define D_MODEL 1024
#define NH 16
#define DKH 64
#define SEQ 2048
#define NB 2
#define NTOK (NB * SEQ)
#define OSC 0.180336880f   // 0.125 * log2(e)

typedef float f32x4 __attribute__((ext_vector_type(4)));
typedef short bf16x8 __attribute__((ext_vector_type(8)));

static __device__ __forceinline__ unsigned short f2bf(float x) {
    union { float f; unsigned int u; } c; c.f = x;
    unsigned int r = (c.u + 0x7FFFu + ((c.u >> 16) & 1u)) >> 16;
    return (unsigned short)r;
}
static __device__ __forceinline__ unsigned int pack2(float a, float b) {
    return (unsigned int)f2bf(a) | ((unsigned int)f2bf(b) << 16);
}
static __device__ __forceinline__ unsigned int pack2rn(float a, float b) {
    union { float f; unsigned int u; } ca, cb; ca.f = a; cb.f = b;
    return __builtin_amdgcn_perm(cb.u + 0x8000u, ca.u + 0x8000u, 0x07060302u);
}
// truncating pack (1 inst) — inner-loop P only (P>0, bias ~2^-9)
static __device__ __forceinline__ unsigned int pack2tr(float a, float b) {
    union { float f; unsigned int u; } ca, cb; ca.f = a; cb.f = b;
    return __builtin_amdgcn_perm(cb.u, ca.u, 0x07060302u);
}
static __device__ __forceinline__ float bflo(unsigned int u) {
    union { unsigned int x; float f; } c; c.x = u << 16; return c.f;
}
static __device__ __forceinline__ float bfhi(unsigned int u) {
    union { unsigned int x; float f; } c; c.x = u & 0xFFFF0000u; return c.f;
}
static __device__ __forceinline__ f32x4 mfma16(uint4 a, uint4 b, f32x4 c) {
    return __builtin_amdgcn_mfma_f32_16x16x32_bf16(
        __builtin_bit_cast(bf16x8, a), __builtin_bit_cast(bf16x8, b), c, 0, 0, 0);
}
static __device__ __forceinline__ void gl_lds16(const unsigned short* g, unsigned short* l) {
    __builtin_amdgcn_global_load_lds(
        (const __attribute__((address_space(1))) unsigned int*)g,
        (__attribute__((address_space(3))) unsigned int*)l, 16, 0, 0);
}
static __device__ __forceinline__ int fsw(int row) {
    return (row & 7) ^ ((row >> 2) & 7);
}

// ---------------- fp32 -> bf16: x + three W's in ONE dispatch ----------------
// blocks [0,2048): x -> xb.  blocks [2048,3584): Wq/Wk/Wv -> Wb3.
__global__ __launch_bounds__(256) void cvt4(
    const float* __restrict__ x, const float* __restrict__ w0,
    const float* __restrict__ w1, const float* __restrict__ w2,
    unsigned short* __restrict__ xb, unsigned short* __restrict__ Wb3)
{
    int bid = blockIdx.x;
    const float* src;
    unsigned short* dst;
    size_t i;
    if (bid < 2048) {
        src = x; dst = xb;
        i = ((size_t)bid * 256 + threadIdx.x) * 8;
    } else {
        int r = bid - 2048;
        int sel = r >> 9, blk = r & 511;
        src = (sel == 0) ? w0 : (sel == 1) ? w1 : w2;
        dst = Wb3 + (size_t)sel * D_MODEL * D_MODEL;
        i = ((size_t)blk * 256 + threadIdx.x) * 8;
    }
    float4 a = *(const float4*)(src + i);
    float4 b = *(const float4*)(src + i + 4);
    uint4 p = { pack2(a.x, a.y), pack2(a.z, a.w), pack2(b.x, b.y), pack2(b.z, b.w) };
    *(uint4*)(dst + i) = p;
}

// ---------------- fp32 -> bf16 copy (KS==1 fallback for Wo) ----------------
__global__ __launch_bounds__(256) void cvt_k(const float* __restrict__ x,
                                             unsigned short* __restrict__ xb)
{
    size_t i = ((size_t)blockIdx.x * 256 + threadIdx.x) * 8;
    float4 a = *(const float4*)(x + i);
    float4 b = *(const float4*)(x + i + 4);
    uint4 p = { pack2(a.x, a.y), pack2(a.z, a.w), pack2(b.x, b.y), pack2(b.z, b.w) };
    *(uint4*)(xb + i) = p;
}

// ---------------- fused QKV GEMM, 128x64 tile, XCD-partitioned ----------------
// sel: 0 Q (osc=OSC, per-head), 1 K (per-head), 2 V (Vt transpose).
// R19: 1536 blocks = 6 blocks/CU = 24 waves/CU. Waves 2m x 2n; per wave
// 64m x 32n (acc[4][2]). xcd = (mg 0..3)*2 + (sg 0..1); slot m-inner.
__global__ __launch_bounds__(256) void gemm_qkv4(
    const unsigned short* __restrict__ A, const unsigned short* __restrict__ Wb3,
    const float* __restrict__ bq, const float* __restrict__ bk,
    const float* __restrict__ bv, unsigned short* __restrict__ Qh,
    unsigned short* __restrict__ Kh, unsigned short* __restrict__ Vt)
{
    __shared__ unsigned short lds[12288];   // 24 KB: lA 128x64 | lB 64x64
    unsigned short* lA = lds;          // 8192 u16
    unsigned short* lB = lds + 8192;   // 4096 u16
    const int tid = threadIdx.x;
    const int wv = tid >> 6, lane = tid & 63, quad = lane >> 4, lm = lane & 15;
    const int wm = wv >> 1, wn = wv & 1;
    const int bid = blockIdx.x;
    const int xcd = bid & 7, slot = bid >> 3;      // slot 0..191
    const int mg = xcd >> 1, sg = xcd & 1;
    const int mtile = mg * 8 + (slot & 7);         // 0..31
    const int sn = sg * 24 + (slot >> 3);          // 0..47
    const int sel = sn >> 4;                       // 0..2
    const int ncol = sn & 15;                      // 0..15
    const int m0 = mtile * 128, n0 = ncol * 64;
    const int sub = lane >> 3, chl = (lane & 7) ^ sub;
    const unsigned short* Wb = Wb3 + (size_t)sel * D_MODEL * D_MODEL;
    const float* bias = (sel == 0) ? bq : (sel == 1) ? bk : bv;
    const float osc = (sel == 0) ? OSC : 1.0f;

    f32x4 acc[4][2] = {};

    for (int k0 = 0; k0 < D_MODEL; k0 += 64) {
        __syncthreads();
#pragma unroll
        for (int j = 0; j < 4; ++j) {
            int rbase = wv * 32 + j * 8;
            gl_lds16(A + (size_t)(m0 + rbase + sub) * D_MODEL + k0 + chl * 8,
                     &lA[rbase * 64]);
        }
#pragma unroll
        for (int j = 0; j < 2; ++j) {
            int rbase = wv * 16 + j * 8;
            gl_lds16(Wb + (size_t)(n0 + rbase + sub) * D_MODEL + k0 + chl * 8,
                     &lB[rbase * 64]);
        }
        __syncthreads();
#pragma unroll
        for (int ks = 0; ks < 2; ++ks) {
            uint4 af[4];
#pragma unroll
            for (int mt = 0; mt < 4; ++mt)
                af[mt] = *(const uint4*)&lA[(wm * 64 + mt * 16 + lm) * 64 +
                                            ((ks * 4 + quad) ^ (lm & 7)) * 8];
#pragma unroll
            for (int nt = 0; nt < 2; ++nt) {
                uint4 bf = *(const uint4*)&lB[(wn * 32 + nt * 16 + lm) * 64 +
                                              ((ks * 4 + quad) ^ (lm & 7)) * 8];
#pragma unroll
                for (int mt = 0; mt < 4; ++mt)
                    acc[mt][nt] = mfma16(af[mt], bf, acc[mt][nt]);
            }
        }
    }

    if (sel < 2) {
        unsigned short* out = (sel == 0) ? Qh : Kh;
#pragma unroll
        for (int nt = 0; nt < 2; ++nt) {
            int n = n0 + wn * 32 + nt * 16 + lm;
            float bvv = bias[n];
            int h = n >> 6, d = n & 63;
#pragma unroll
            for (int mt = 0; mt < 4; ++mt)
#pragma unroll
                for (int r = 0; r < 4; ++r) {
                    int m = m0 + wm * 64 + mt * 16 + quad * 4 + r;
                    int b = m >> 11, q = m & 2047;
                    out[((size_t)(b * NH + h) * SEQ + q) * DKH + d] =
                        f2bf((acc[mt][nt][r] + bvv) * osc);
                }
        }
    } else {
        __syncthreads();
        unsigned short* T = lds;   // 64 n x 128 m u16 (16 KB)
#pragma unroll
        for (int nt = 0; nt < 2; ++nt) {
            int nl = wn * 32 + nt * 16 + lm;
            float bvv = bias[n0 + nl];
#pragma unroll
            for (int mt = 0; mt < 4; ++mt) {
                int ml = wm * 64 + mt * 16 + quad * 4;
                uint2 p = { pack2rn(acc[mt][nt][0] + bvv, acc[mt][nt][1] + bvv),
                            pack2rn(acc[mt][nt][2] + bvv, acc[mt][nt][3] + bvv) };
                *(uint2*)&T[nl * 128 + ml] = p;
            }
        }
        __syncthreads();
        int row = tid >> 2, seg = tid & 3;     // 64 rows x 4 segs of 32 u16
        int b = m0 >> 11, s0 = m0 & 2047;
        unsigned short* dst = Vt + ((size_t)(b * D_MODEL) + n0 + row) * SEQ + s0 + seg * 32;
        const unsigned short* src = &T[row * 128 + seg * 32];
#pragma unroll
        for (int i = 0; i < 4; ++i)
            *(uint4*)(dst + i * 8) = *(const uint4*)(src + i * 8);
    }
}

// ---------------- psum_wo: fold KS partials + convert Wo, ONE dispatch ----------
// blocks [0,2048): psum. blocks [2048,2560): Wo fp32->bf16.
template <int KS>
__global__ __launch_bounds__(256) void psum_wo(
    const unsigned short* __restrict__ OP, unsigned short* __restrict__ OPs,
    const float* __restrict__ Wo, unsigned short* __restrict__ WoB)
{
    int bid = blockIdx.x;
    if (bid >= 2048) {
        size_t i = ((size_t)(bid - 2048) * 256 + threadIdx.x) * 8;
        float4 a = *(const float4*)(Wo + i);
        float4 b = *(const float4*)(Wo + i + 4);
        uint4 p = { pack2(a.x, a.y), pack2(a.z, a.w), pack2(b.x, b.y), pack2(b.z, b.w) };
        *(uint4*)(WoB + i) = p;
        return;
    }
    const size_t M = (size_t)NTOK * D_MODEL;
    size_t i = ((size_t)bid * 256 + threadIdx.x) * 8;
    uint4 a = *(const uint4*)(OP + i);
    float lo0 = bflo(a.x), hi0 = bfhi(a.x), lo1 = bflo(a.y), hi1 = bfhi(a.y);
    float lo2 = bflo(a.z), hi2 = bfhi(a.z), lo3 = bflo(a.w), hi3 = bfhi(a.w);
#pragma unroll
    for (int p = 1; p < KS; ++p) {
        uint4 u = *(const uint4*)(OP + p * M + i);
        lo0 += bflo(u.x); hi0 += bfhi(u.x); lo1 += bflo(u.y); hi1 += bfhi(u.y);
        lo2 += bflo(u.z); hi2 += bfhi(u.z); lo3 += bflo(u.w); hi3 += bfhi(u.w);
    }
    uint4 o = { pack2(lo0, hi0), pack2(lo1, hi1), pack2(lo2, hi2), pack2(lo3, hi3) };
    *(uint4*)(OPs + i) = o;
}

// ---------------- out-proj: A = folded ctx (bf16), B = Wo bf16; fp32 out --------
// R11 tile: 128x64, waves 2m x 2n (acc[4][2]); R17 XCD m-inner partition.
// R18: double-buffered LDS (48 KB, still 2 blocks/CU at grid 512 — free):
// stage(next) -> compute(cur) -> ONE barrier.
__global__ __launch_bounds__(256) void gemm_osum3(
    const unsigned short* __restrict__ OPs, const unsigned short* __restrict__ WoB,
    const float* __restrict__ bias, float* __restrict__ out)
{
    __shared__ unsigned short lds[2][12288];   // 48 KB: per buf lA 128x64 | lB 64x64
    const int tid = threadIdx.x;
    const int wv = tid >> 6, lane = tid & 63, quad = lane >> 4, lm = lane & 15;
    const int wm = wv >> 1, wn = wv & 1;
    const int bid = blockIdx.x;
    const int xcd = bid & 7, slot = bid >> 3;          // slot 0..63
    const int mg = xcd >> 1, ng = xcd & 1;
    const int mtile = mg * 8 + (slot & 7);             // 0..31
    const int ncol = ng * 8 + (slot >> 3);             // 0..15
    const int m0 = mtile * 128, n0 = ncol * 64;
    const int sub = lane >> 3, chl = (lane & 7) ^ sub;
    const int b = m0 >> 11, q0 = m0 & 2047;

    f32x4 acc[4][2] = {};

    auto stage = [&](int buf, int k0) {
        const int h = k0 >> 6;
        const unsigned short* Ab = OPs + ((size_t)(b * NH + h) * SEQ + q0) * DKH;
        unsigned short* lA = lds[buf];
        unsigned short* lB = lds[buf] + 8192;
#pragma unroll
        for (int j = 0; j < 4; ++j) {
            int rbase = wv * 32 + j * 8;
            gl_lds16(Ab + (size_t)(rbase + sub) * DKH + chl * 8, &lA[rbase * 64]);
        }
#pragma unroll
        for (int j = 0; j < 2; ++j) {
            int rbase = wv * 16 + j * 8;
            gl_lds16(WoB + (size_t)(n0 + rbase + sub) * D_MODEL + k0 + chl * 8,
                     &lB[rbase * 64]);
        }
    };

    stage(0, 0);
    __syncthreads();

    for (int k0 = 0; k0 < D_MODEL; k0 += 64) {
        const int cur = (k0 >> 6) & 1;
        if (k0 + 64 < D_MODEL)
            stage(cur ^ 1, k0 + 64);   // overlaps this step's compute
        const unsigned short* lA = lds[cur];
        const unsigned short* lB = lds[cur] + 8192;
#pragma unroll
        for (int ks = 0; ks < 2; ++ks) {
            uint4 af[4];
#pragma unroll
            for (int mt = 0; mt < 4; ++mt)
                af[mt] = *(const uint4*)&lA[(wm * 64 + mt * 16 + lm) * 64 +
                                            ((ks * 4 + quad) ^ (lm & 7)) * 8];
#pragma unroll
            for (int nt = 0; nt < 2; ++nt) {
                uint4 bf = *(const uint4*)&lB[(wn * 32 + nt * 16 + lm) * 64 +
                                              ((ks * 4 + quad) ^ (lm & 7)) * 8];
#pragma unroll
                for (int mt = 0; mt < 4; ++mt)
                    acc[mt][nt] = mfma16(af[mt], bf, acc[mt][nt]);
            }
        }
        __syncthreads();   // next-tile stage landed; buffer reuse safe
    }
#pragma unroll
    for (int nt = 0; nt < 2; ++nt) {
        int n = n0 + wn * 32 + nt * 16 + lm;
        float bv = bias[n];
#pragma unroll
        for (int mt = 0; mt < 4; ++mt)
#pragma unroll
            for (int r = 0; r < 4; ++r) {
                int m = m0 + wm * 64 + mt * 16 + quad * 4 + r;
                out[(size_t)m * D_MODEL + n] = acc[mt][nt][r] + bv;
            }
    }
}

// ---------------- zker2: lrz[b][q][k] = -log2(sum_h exp2(S_scaled)) ----------
// R10/R12 (proven): double-buffered K staging + next-head Q prefetch;
// 1 barrier/head. (R16: 4 blocks/CU variant was null — structure, not TLP, binds.)
__global__ __launch_bounds__(256) void zker2(
    const unsigned short* __restrict__ Qh, const unsigned short* __restrict__ Kh,
    unsigned short* __restrict__ rz)
{
    __shared__ unsigned short lK[2][128 * 64];  // 32 KB
    const int tid = threadIdx.x;
    const int wv = tid >> 6, lane = tid & 63, quad = lane >> 4, lm = lane & 15;
    // swizzle: XCD owns 4 (b,kb) columns x all 16 qb (qb adjacent -> K slab shared)
    const int lid = blockIdx.x;
    const int xcd = lid & 7, slot = lid >> 3;
    const int qb = slot & 15, col = xcd * 4 + (slot >> 4);
    const int b = col >> 4, kb = col & 15;
    const int q0 = qb * 128, k0 = kb * 128;
    const int srow = tid >> 3, sc = tid & 7;

    f32x4 z[2][8] = {};

    auto stagek = [&](int buf, int hh) {
        const size_t kbase = ((size_t)(b * NH + hh) * SEQ + k0) * DKH;
#pragma unroll
        for (int j = 0; j < 4; ++j) {
            int row = j * 32 + srow;
            int g = sc ^ fsw(row);
            gl_lds16(Kh + kbase + (size_t)row * 64 + g * 8,
                     &lK[buf][(j * 32 + wv * 8) * 64]);
        }
    };
    auto loadq = [&](uint4 (&bqr)[2][2], int hh) {
#pragma unroll
        for (int qs = 0; qs < 2; ++qs) {
            const unsigned short* qp = Qh +
                ((size_t)(b * NH + hh) * SEQ + q0 + wv * 32 + qs * 16 + lm) * DKH + quad * 8;
            bqr[qs][0] = *(const uint4*)qp;
            bqr[qs][1] = *(const uint4*)(qp + 32);
        }
    };

    uint4 bq[2][2];
    stagek(0, 0);
    loadq(bq, 0);
    __syncthreads();

    for (int h = 0; h < NH; ++h) {
        const int cur = h & 1;
        uint4 bqn[2][2];
        if (h + 1 < NH) {
            stagek(cur ^ 1, h + 1);   // overlaps this head's compute
            loadq(bqn, h + 1);
        }
        const unsigned short* cK = lK[cur];
#pragma unroll
        for (int kt = 0; kt < 8; ++kt) {
            int krow = kt * 16 + lm;
            uint4 a0 = *(const uint4*)&cK[krow * 64 + ((quad) ^ fsw(krow)) * 8];
            uint4 a1 = *(const uint4*)&cK[krow * 64 + ((4 + quad) ^ fsw(krow)) * 8];
#pragma unroll
            for (int qs = 0; qs < 2; ++qs) {
                f32x4 sf = {0.f, 0.f, 0.f, 0.f};
                __builtin_amdgcn_s_setprio(1);
                sf = mfma16(a0, bq[qs][0], sf);
                sf = mfma16(a1, bq[qs][1], sf);
                __builtin_amdgcn_s_setprio(0);
#pragma unroll
                for (int r = 0; r < 4; ++r)
                    z[qs][kt][r] += __builtin_amdgcn_exp2f(sf[r]);
            }
        }
        __syncthreads();   // next K slab landed (issued a full compute phase ago)
        if (h + 1 < NH) {
#pragma unroll
            for (int qs = 0; qs < 2; ++qs) {
                bq[qs][0] = bqn[qs][0];
                bq[qs][1] = bqn[qs][1];
            }
        }
    }
#pragma unroll
    for (int qs = 0; qs < 2; ++qs) {
        int q = q0 + wv * 32 + qs * 16 + lm;
#pragma unroll
        for (int kt = 0; kt < 8; ++kt) {
            int k = k0 + kt * 16 + quad * 4;
            float l0 = __builtin_amdgcn_logf(z[qs][kt][0]);
            float l1 = __builtin_amdgcn_logf(z[qs][kt][1]);
            float l2 = __builtin_amdgcn_logf(z[qs][kt][2]);
            float l3 = __builtin_amdgcn_logf(z[qs][kt][3]);
            uint2 st = { pack2rn(-l0, -l1), pack2rn(-l2, -l3) };
            *(uint2*)(rz + (size_t)(b * SEQ + q) * SEQ + k) = st;
        }
    }
}

// ---------------- attn4: per-head attention; lrz as MFMA C-init; XCD-swizzled ----------
// R12: exact R9 body (VGPR 64, 16KB LDS, 8 blocks/CU).
// R15 (KS=4): xcd owns one (b,ksl); slot = qb*16 + h (FETCH 105->40MB).
template <int KS>
__global__ __launch_bounds__(256) void attn4(
    const unsigned short* __restrict__ Qh, const unsigned short* __restrict__ Kh,
    const unsigned short* __restrict__ Vt, const unsigned short* __restrict__ rz,
    unsigned short* __restrict__ OP)
{
    __shared__ unsigned short lK[64 * 64];   // 8 KB
    __shared__ unsigned short lV[64 * 64];   // 8 KB
    const int tid = threadIdx.x;
    const int wv = tid >> 6, lane = tid & 63, quad = lane >> 4, lm = lane & 15;
    const int lid = blockIdx.x;
    int b, h, ksl, qb;
    if constexpr (KS == 4) {
        // R15 swizzle: 2048 = 8 xcd x 256 slot; xcd <-> (b,ksl); slot = qb*16+h
        const int xcd = lid & 7, slot = lid >> 3;
        b = xcd >> 2; ksl = xcd & 3;
        qb = slot >> 4; h = slot & 15;
    } else {
        // generic swizzle: XCD owns 4*KS (bh,ksl) combos x all 16 qb
        const int xcd = lid & 7, slot = lid >> 3;
        qb = slot & 15;
        const int combo = xcd * (4 * KS) + (slot >> 4);
        const int bh = combo / KS; ksl = combo % KS;
        b = bh >> 4; h = bh & 15;
    }
    const int q0 = qb * 128;
    const int NIT = (SEQ / KS) / 64;
    const int kbeg = ksl * (SEQ / KS);
    const int q0w = q0 + wv * 32;
    const size_t hb = (size_t)(b * NH + h) * SEQ;
    const int srow = tid >> 3, sc = tid & 7;

    uint4 qf[2][2];
#pragma unroll
    for (int qs = 0; qs < 2; ++qs)
#pragma unroll
        for (int ks = 0; ks < 2; ++ks)
            qf[qs][ks] = *(const uint4*)(Qh + (hb + q0w + qs * 16 + lm) * DKH +
                                         ks * 32 + quad * 8);

    const int perm = ((lm >> 2) * 8) + (lm & 3);
    f32x4 oa[4][2] = {};

    for (int kt = 0; kt < NIT; ++kt) {
        const int kbase = kbeg + kt * 64;
        __syncthreads();
#pragma unroll
        for (int j = 0; j < 2; ++j) {
            int row = j * 32 + srow;
            int g = sc ^ fsw(row);
            gl_lds16(Kh + (hb + kbase + row) * DKH + g * 8,
                     &lK[(j * 32 + wv * 8) * 64]);
        }
#pragma unroll
        for (int j = 0; j < 2; ++j) {
            int row = j * 32 + srow;
            int g = sc ^ fsw(row);
            gl_lds16(Vt + ((size_t)(b * D_MODEL) + h * DKH + row) * SEQ + kbase + g * 8,
                     &lV[(j * 32 + wv * 8) * 64]);
        }
        uint4 rv[2][2];
#pragma unroll
        for (int qs = 0; qs < 2; ++qs)
#pragma unroll
            for (int gr = 0; gr < 2; ++gr)
                rv[gr][qs] = *(const uint4*)(rz +
                    (size_t)(b * SEQ + q0w + qs * 16 + lm) * SEQ +
                    kbase + gr * 32 + quad * 8);
        __syncthreads();

#pragma unroll
        for (int gr = 0; gr < 2; ++gr) {
            // C-init with lrz: sf = QK^T_scaled - log2(Z); then p = exp2(sf)
            f32x4 sf[2][2];
#pragma unroll
            for (int qs = 0; qs < 2; ++qs) {
                uint4 rq = rv[gr][qs];
                sf[0][qs][0] = bflo(rq.x); sf[0][qs][1] = bfhi(rq.x);
                sf[0][qs][2] = bflo(rq.y); sf[0][qs][3] = bfhi(rq.y);
                sf[1][qs][0] = bflo(rq.z); sf[1][qs][1] = bfhi(rq.z);
                sf[1][qs][2] = bflo(rq.w); sf[1][qs][3] = bfhi(rq.w);
            }
#pragma unroll
            for (int sel = 0; sel < 2; ++sel) {
                int key = gr * 32 + perm + sel * 4;
#pragma unroll
                for (int ks = 0; ks < 2; ++ks) {
                    uint4 kfv = *(const uint4*)&lK[key * 64 +
                                                   ((ks * 4 + quad) ^ fsw(key)) * 8];
                    sf[sel][0] = mfma16(kfv, qf[0][ks], sf[sel][0]);
                    sf[sel][1] = mfma16(kfv, qf[1][ks], sf[sel][1]);
                }
            }
            uint4 pk[2];
#pragma unroll
            for (int qs = 0; qs < 2; ++qs) {
                float p00 = __builtin_amdgcn_exp2f(sf[0][qs][0]);
                float p01 = __builtin_amdgcn_exp2f(sf[0][qs][1]);
                float p02 = __builtin_amdgcn_exp2f(sf[0][qs][2]);
                float p03 = __builtin_amdgcn_exp2f(sf[0][qs][3]);
                float p10 = __builtin_amdgcn_exp2f(sf[1][qs][0]);
                float p11 = __builtin_amdgcn_exp2f(sf[1][qs][1]);
                float p12 = __builtin_amdgcn_exp2f(sf[1][qs][2]);
                float p13 = __builtin_amdgcn_exp2f(sf[1][qs][3]);
                pk[qs].x = pack2tr(p00, p01);
                pk[qs].y = pack2tr(p02, p03);
                pk[qs].z = pack2tr(p10, p11);
                pk[qs].w = pack2tr(p12, p13);
            }
#pragma unroll
            for (int ct = 0; ct < 4; ++ct) {
                int vrow = ct * 16 + lm;
                uint4 vfv = *(const uint4*)&lV[vrow * 64 +
                                               ((gr * 4 + quad) ^ fsw(vrow)) * 8];
                oa[ct][0] = mfma16(vfv, pk[0], oa[ct][0]);
                oa[ct][1] = mfma16(vfv, pk[1], oa[ct][1]);
            }
        }
    }

    unsigned short* op = OP + (size_t)ksl * NTOK * D_MODEL;
#pragma unroll
    for (int ct = 0; ct < 4; ++ct)
#pragma unroll
        for (int qs = 0; qs < 2; ++qs) {
            uint2 st = { pack2rn(oa[ct][qs][0], oa[ct][qs][1]),
                         pack2rn(oa[ct][qs][2], oa[ct][qs][3]) };
            *(uint2*)(op + (hb + q0w + qs * 16 + lm) * DKH + ct * 16 + quad * 4) = st;
        }
}

extern "C" void kernel_launch(void* const* d_in, const int* in_sizes, int n_in,
                              void* d_out, int out_size, void* d_ws, size_t ws_size,
                              hipStream_t stream)
{
    const float* x  = (const float*)d_in[0];
    const float* Wq = (const float*)d_in[1];
    const float* bq = (const float*)d_in[2];
    const float* Wk = (const float*)d_in[3];
    const float* bk = (const float*)d_in[4];
    const float* Wv = (const float*)d_in[5];
    const float* bv = (const float*)d_in[6];
    const float* Wo = (const float*)d_in[7];
    const float* bo = (const float*)d_in[8];
    float* out = (float*)d_out;

    const size_t M  = (size_t)NTOK * D_MODEL;      // 4,194,304
    const size_t RZ = (size_t)NB * SEQ * SEQ;      // 8,388,608
    unsigned short* ws = (unsigned short*)d_ws;
    unsigned short* rzb = ws;            // lrz; also xb early, WoB late
    unsigned short* xb  = ws;
    unsigned short* Qh  = ws + RZ;       // per-head [(b,h,q)][dk], Q pre-scaled by OSC
    unsigned short* Kh  = Qh + M;
    unsigned short* Vt  = Kh + M;        // [b][c][s]
    unsigned short* OP  = Vt + M;        // KS per-head partials; early alias: Wb3
    unsigned short* Wb3 = OP;
    unsigned short* OPs = Qh;            // folded ctx (Qh dead after attn4)
    unsigned short* WoB = rzb;           // bf16 Wo (lrz dead after attn4)

    const size_t need4 = (RZ + 3 * M + 4 * M) * sizeof(unsigned short);  // 75.5 MB
    const size_t need2 = (RZ + 3 * M + 2 * M) * sizeof(unsigned short);  // 58.7 MB
    const int KS = (ws_size >= need4) ? 4 : (ws_size >= need2) ? 2 : 1;

    cvt4<<<3584, 256, 0, stream>>>(x, Wq, Wk, Wv, xb, Wb3);
    gemm_qkv4<<<1536, 256, 0, stream>>>(xb, Wb3, bq, bk, bv, Qh, Kh, Vt);
    zker2<<<512, 256, 0, stream>>>(Qh, Kh, rzb);
    if (KS == 4)      attn4<4><<<2048, 256, 0, stream>>>(Qh, Kh, Vt, rzb, OP);
    else if (KS == 2) attn4<2><<<1024, 256, 0, stream>>>(Qh, Kh, Vt, rzb, OP);
    else              attn4<1><<<512, 256, 0, stream>>>(Qh, Kh, Vt, rzb, OP);
    if (KS == 4)      psum_wo<4><<<2560, 256, 0, stream>>>(OP, OPs, Wo, WoB);
    else if (KS == 2) psum_wo<2><<<2560, 256, 0, stream>>>(OP, OPs, Wo, WoB);
    else {
        cvt_k<<<512, 256, 0, stream>>>(Wo, WoB);
        OPs = OP;
    }
    gemm_osum3<<<dim3(512), 256, 0, stream>>>(OPs, WoB, bo, out);
}